// Round 10
// baseline (253.169 us; speedup 1.0000x reference)
//
#include <hip/hip_runtime.h>
#include <math.h>

#define DIM   256
#define NLVL  5
#define H     50000          // split point: A does [0,H), B does [H,N)
#define NBA   1024           // blocks for half A (4096 waves, 5-stream lockstep)
#define NBB   1024           // blocks for half B (per-level waves, single stream)
#define PSTR  1280           // partial slots per level (1024 A + <=205 B)

struct Ptrs {
  const float* p[NLVL];
  const float* W[NLVL];
  const float* b[NLVL];
};

// ---- pass 1 half A: rows [0,H). 5-stream lockstep per wave (R3 structure). ----
__global__ __launch_bounds__(256) void k_p1a(Ptrs pt, float* __restrict__ logits,
                                             float2* __restrict__ part, int N)
{
  const int lane = threadIdx.x & 63;
  const int wid  = threadIdx.x >> 6;

  float4 wf[NLVL];
  float  bias[NLVL], m[NLVL], s[NLVL];
  #pragma unroll
  for (int l = 0; l < NLVL; l++) {
    wf[l]   = *reinterpret_cast<const float4*>(pt.W[l] + lane * 4);
    bias[l] = *pt.b[l];
    m[l]    = -INFINITY;
    s[l]    = 0.f;
  }

  const int gw  = blockIdx.x * 4 + wid;        // 0..4095
  const int off = lane * 4;
  for (int n = gw; n < H; n += NBA * 4) {
    float d[NLVL];
    #pragma unroll
    for (int l = 0; l < NLVL; l++) {
      float4 pv = *reinterpret_cast<const float4*>(pt.p[l] + (size_t)n * DIM + off);
      d[l] = pv.x * wf[l].x + pv.y * wf[l].y + pv.z * wf[l].z + pv.w * wf[l].w;
    }
    #pragma unroll
    for (int o = 32; o; o >>= 1) {
      #pragma unroll
      for (int l = 0; l < NLVL; l++) d[l] += __shfl_xor(d[l], o);
    }
    #pragma unroll
    for (int l = 0; l < NLVL; l++) d[l] += bias[l];
    float sv = d[0];
    sv = (lane == 1) ? d[1] : sv;
    sv = (lane == 2) ? d[2] : sv;
    sv = (lane == 3) ? d[3] : sv;
    sv = (lane == 4) ? d[4] : sv;
    if (lane < NLVL) logits[(size_t)lane * N + n] = sv;
    #pragma unroll
    for (int l = 0; l < NLVL; l++) {
      float Mn = fmaxf(m[l], d[l]);
      s[l] = s[l] * __expf(m[l] - Mn) + __expf(d[l] - Mn);
      m[l] = Mn;
    }
  }

  __shared__ float smM[4][NLVL], smS[4][NLVL];
  if (lane == 0) {
    #pragma unroll
    for (int l = 0; l < NLVL; l++) { smM[wid][l] = m[l]; smS[wid][l] = s[l]; }
  }
  __syncthreads();
  if (threadIdx.x < NLVL) {
    const int l = threadIdx.x;
    float M = smM[0][l], S = smS[0][l];
    #pragma unroll
    for (int i = 1; i < 4; i++) {
      float Mn = fmaxf(M, smM[i][l]);
      if (Mn > -INFINITY) { S = S * __expf(M - Mn) + smS[i][l] * __expf(smM[i][l] - Mn); M = Mn; }
    }
    part[l * PSTR + blockIdx.x] = make_float2(M, S);
  }
}

// ---- pass 1 half B: rows [H,N). One level per wave (single read stream). ----
__global__ __launch_bounds__(256) void k_p1b(Ptrs pt, float* __restrict__ logits,
                                             float2* __restrict__ part, int N)
{
  const int lane = threadIdx.x & 63;
  const int wid  = threadIdx.x >> 6;
  const int lvl  = blockIdx.x % NLVL;
  const int q    = blockIdx.x / NLVL;          // 0..204 (or 203 for lvl 4)
  const int nB   = (1028 - lvl) / 5;           // blocks for this level: 205,205,205,205,204

  const float* __restrict__ p = pt.p[lvl];
  const float4 wf  = *reinterpret_cast<const float4*>(pt.W[lvl] + lane * 4);
  const float bias = *pt.b[lvl];

  float m = -INFINITY, s = 0.f;
  const int gw  = q * 4 + wid;
  const int nw  = nB * 4;
  const int off = lane * 4;
  for (int n = H + gw; n < N; n += nw) {
    float4 pv = *reinterpret_cast<const float4*>(p + (size_t)n * DIM + off);
    float d = pv.x * wf.x + pv.y * wf.y + pv.z * wf.z + pv.w * wf.w;
    #pragma unroll
    for (int o = 32; o; o >>= 1) d += __shfl_xor(d, o);
    d += bias;
    if (lane == 0) logits[(size_t)lvl * N + n] = d;
    float Mn = fmaxf(m, d);
    s = s * __expf(m - Mn) + __expf(d - Mn);
    m = Mn;
  }

  __shared__ float smM[4], smS[4];
  if (lane == 0) { smM[wid] = m; smS[wid] = s; }
  __syncthreads();
  if (threadIdx.x == 0) {
    float M = smM[0], S = smS[0];
    #pragma unroll
    for (int i = 1; i < 4; i++) {
      float Mn = fmaxf(M, smM[i]);
      if (Mn > -INFINITY) { S = S * __expf(M - Mn) + smS[i] * __expf(smM[i] - Mn); M = Mn; }
    }
    part[lvl * PSTR + NBA + q] = make_float2(M, S);
  }
}

// ---- combine partials per level -> (M, S) ----
__global__ __launch_bounds__(320) void k_reduce(const float2* __restrict__ part,
                                                float2* __restrict__ stats)
{
  const int lvl  = threadIdx.x >> 6;
  const int lane = threadIdx.x & 63;
  const int tot  = NBA + (1028 - lvl) / 5;     // A slots + B slots for this level
  float m = -INFINITY, s = 0.f;
  for (int i = lane; i < tot; i += 64) {
    float2 ps = part[lvl * PSTR + i];
    float Mn = fmaxf(m, ps.x);
    if (Mn > -INFINITY) { s = s * __expf(m - Mn) + ps.y * __expf(ps.x - Mn); m = Mn; }
  }
  #pragma unroll
  for (int o = 32; o; o >>= 1) {
    float mo = __shfl_xor(m, o), so = __shfl_xor(s, o);
    float Mn = fmaxf(m, mo);
    if (Mn > -INFINITY) { s = s * __expf(m - Mn) + so * __expf(mo - Mn); m = Mn; }
  }
  if (lane == 0) stats[lvl] = make_float2(m, s);
}

// ---- pass 2: weights + fused output ----
__global__ __launch_bounds__(256) void k_pass2(Ptrs pt, const float* __restrict__ logits,
                                               const float2* __restrict__ stats,
                                               float* __restrict__ out, int N)
{
  const int lane = threadIdx.x & 63;
  const int wid  = threadIdx.x >> 6;
  float M[NLVL], Si[NLVL];
  #pragma unroll
  for (int l = 0; l < NLVL; l++) { float2 st = stats[l]; M[l] = st.x; Si[l] = 1.f / st.y; }

  const int gw  = blockIdx.x * 4 + wid;
  const int nw  = 2048 * 4;
  const int off = lane * 4;
  for (int n = gw; n < N; n += nw) {
    float wl[NLVL], t = 0.f;
    #pragma unroll
    for (int l = 0; l < NLVL; l++) {
      float e = __expf(logits[(size_t)l * N + n] - M[l]) * Si[l];
      wl[l] = e; t += e;
    }
    const float inv = 1.f / t;
    float4 acc = make_float4(0.f, 0.f, 0.f, 0.f);
    #pragma unroll
    for (int l = 0; l < NLVL; l++) {
      float4 pv = *reinterpret_cast<const float4*>(pt.p[l] + (size_t)n * DIM + off);
      float c = wl[l] * inv;
      acc.x += c * pv.x; acc.y += c * pv.y; acc.z += c * pv.z; acc.w += c * pv.w;
    }
    *reinterpret_cast<float4*>(out + (size_t)n * DIM + off) = acc;
  }
}

extern "C" void kernel_launch(void* const* d_in, const int* in_sizes, int n_in,
                              void* d_out, int out_size, void* d_ws, size_t ws_size,
                              hipStream_t stream)
{
  Ptrs pt;
  for (int l = 0; l < NLVL; l++) {
    pt.p[l] = (const float*)d_in[l];
    pt.W[l] = (const float*)d_in[5 + 2 * l];
    pt.b[l] = (const float*)d_in[6 + 2 * l];
  }
  const int N = in_sizes[0] / DIM;             // 100000

  char* ws = (char*)d_ws;
  size_t logits_bytes = (((size_t)NLVL * N * sizeof(float)) + 255) & ~(size_t)255;
  float*  logits = (float*)ws;
  float2* part   = (float2*)(ws + logits_bytes);
  float2* stats  = part + NLVL * PSTR;

  k_p1a   <<<NBA,  256, 0, stream>>>(pt, logits, part, N);
  k_p1b   <<<NBB,  256, 0, stream>>>(pt, logits, part, N);
  k_reduce<<<1,    320, 0, stream>>>(part, stats);
  k_pass2 <<<2048, 256, 0, stream>>>(pt, logits, stats, (float*)d_out, N);
}